// Round 4
// baseline (309.631 us; speedup 1.0000x reference)
//
#include <hip/hip_runtime.h>

#define IMG_H 512
#define IMG_W 512
#define N_IMG 32
#define ROWS  16
#define BANDS (IMG_H / ROWS)      // 32 bands/image
#define STEPS 6                   // 4 row-slides per step = 24 slides per band
#define VROW  520                 // LDS row: load-cols 0..519, 16B-aligned stride
#define NPIX  (32.0f * 512.0f * 512.0f)

struct RowVals { float2 mI, mT, tI, tT; };   // main pair (load-cols 2t,2t+1), tail pair (512+2t, t<2 real)
struct Sums    { float2 I, T, II, TT, IT; };

__device__ __forceinline__ RowVals zero_row() {
    RowVals v;
    v.mI = make_float2(0.f, 0.f); v.mT = v.mI; v.tI = v.mI; v.tT = v.mI;
    return v;
}

__device__ __forceinline__ RowVals load_row(const float* __restrict__ ip,
                                            const float* __restrict__ tp,
                                            int r, int t) {
    RowVals v = zero_row();
    if (r >= 0 && r < IMG_H) {
        const float* irow = ip + (ptrdiff_t)r * IMG_W;
        const float* trow = tp + (ptrdiff_t)r * IMG_W;
        if (t >= 2) {                       // load-cols 2t,2t+1 -> img cols 2t-4,2t-3
            v.mI = *(const float2*)(irow + 2 * t - 4);
            float2 a = *(const float2*)(trow + 2 * t - 4);
            v.mT = make_float2((a.x + 1.f) * 0.5f, (a.y + 1.f) * 0.5f);
        } else {                            // t=0,1: main cols are left-pad; load tail img 508..511
            v.tI = *(const float2*)(irow + 508 + 2 * t);
            float2 a = *(const float2*)(trow + 508 + 2 * t);
            v.tT = make_float2((a.x + 1.f) * 0.5f, (a.y + 1.f) * 0.5f);
        }
    }
    return v;
}

__device__ __forceinline__ void slide(Sums& s, float2 pI, float2 pT, float2 qI, float2 qT) {
    s.I.x  += pI.x - qI.x;            s.I.y  += pI.y - qI.y;
    s.T.x  += pT.x - qT.x;            s.T.y  += pT.y - qT.y;
    s.II.x += pI.x*pI.x - qI.x*qI.x;  s.II.y += pI.y*pI.y - qI.y*qI.y;
    s.TT.x += pT.x*pT.x - qT.x*qT.x;  s.TT.y += pT.y*pT.y - qT.y*qT.y;
    s.IT.x += pI.x*pT.x - qI.x*qT.x;  s.IT.y += pI.y*pT.y - qI.y*qT.y;
}

__device__ __forceinline__ void publish(float* vb, int col, const Sums& s) {
    *(float2*)(vb + 0 * VROW + col) = s.I;
    *(float2*)(vb + 1 * VROW + col) = s.T;
    *(float2*)(vb + 2 * VROW + col) = s.II;
    *(float2*)(vb + 3 * VROW + col) = s.TT;
    *(float2*)(vb + 4 * VROW + col) = s.IT;
}

__device__ __forceinline__ float cc_of(float sI, float sT, float sII, float sTT, float sIT) {
    const float inv81 = 1.0f / 81.0f;
    float u     = sI * inv81;
    float w     = sT * inv81;
    float cross = fmaf(-u, sT, sIT);
    float iv    = fmaf(-u, sI, sII);
    float tv    = fmaf(-w, sT, sTT);
    float den   = fmaf(tv, iv, 1e-5f);
    return cross * cross * __builtin_amdgcn_rcpf(den);
}

__global__ __launch_bounds__(256, 3)
void cc_loss_kernel(const float* __restrict__ in, const float* __restrict__ tg,
                    float* __restrict__ out) {
    __shared__ __align__(16) float vs[4][5][VROW];   // 4 row-snapshots x 5 arrays = 41.6 KB
    __shared__ float red[4];

    const int t    = threadIdx.x;
    const int b    = blockIdx.x >> 5;
    const int band = blockIdx.x & 31;
    const int r0   = band * ROWS;
    const size_t base = (size_t)b * (IMG_H * IMG_W);
    const float* ip = in + base;
    const float* tp = tg + base;

    Sums mn = {}, tl = {};
    float acc = 0.0f;

    RowVals p[4], q[4];
    #pragma unroll
    for (int r = 0; r < 4; ++r) {
        p[r] = load_row(ip, tp, r0 - 4 + r, t);
        q[r] = zero_row();                    // slides 0..3 never evict a real row
    }

    for (int s = 0; s < STEPS; ++s) {
        // ---- V phase: 4 slides, publish snapshots (only once H will consume) ----
        #pragma unroll
        for (int r = 0; r < 4; ++r) {
            slide(mn, p[r].mI, p[r].mT, q[r].mI, q[r].mT);
            if (t < 4) slide(tl, p[r].tI, p[r].tT, q[r].tI, q[r].tT);
            if (s >= 2) {
                publish(&vs[r][0][0], 2 * t, mn);
                if (t < 4) publish(&vs[r][0][0], 512 + 2 * t, tl);
            }
        }

        // ---- prefetch the next step's 4 leading + 4 trailing rows (regs) ----
        if (s + 1 < STEPS) {
            const int jn = r0 - 4 + 4 * (s + 1);
            #pragma unroll
            for (int r = 0; r < 4; ++r) {
                p[r] = load_row(ip, tp, jn + r, t);
                const int qr = jn + r - 9;   // row leaving the 9-window at that slide
                q[r] = load_row(ip, tp, (qr >= r0 - 4) ? qr : -1, t);
            }
        }

        // ---- H phase: 4 output rows, 8 px/thread, 4x ds_read_b128 per array ----
        if (s >= 2) {
            __syncthreads();
            const int m  = t >> 6;                  // snapshot slot / output row 0..3
            const int c0 = 8 * (t & 63);            // first output px col
            const float* vb = &vs[m][0][0] + c0;    // load-cols c0 .. c0+15
            float h[5][8];
            #pragma unroll
            for (int a = 0; a < 5; ++a) {
                const float* rp = vb + a * VROW;
                float4 w0 = *(const float4*)(rp + 0);
                float4 w1 = *(const float4*)(rp + 4);
                float4 w2 = *(const float4*)(rp + 8);
                float4 w3 = *(const float4*)(rp + 12);
                float s0 = ((w0.x + w0.y) + (w0.z + w0.w)) +
                           ((w1.x + w1.y) + (w1.z + w1.w)) + w2.x;
                float s1 = s0 - w0.x + w2.y;
                float s2 = s1 - w0.y + w2.z;
                float s3 = s2 - w0.z + w2.w;
                float s4 = s3 - w0.w + w3.x;
                float s5 = s4 - w1.x + w3.y;
                float s6 = s5 - w1.y + w3.z;
                float s7 = s6 - w1.z + w3.w;
                h[a][0] = s0; h[a][1] = s1; h[a][2] = s2; h[a][3] = s3;
                h[a][4] = s4; h[a][5] = s5; h[a][6] = s6; h[a][7] = s7;
            }
            #pragma unroll
            for (int j = 0; j < 8; ++j)
                acc += cc_of(h[0][j], h[1][j], h[2][j], h[3][j], h[4][j]);
            if (s + 1 < STEPS) __syncthreads();     // protect slots before next publish
        }
    }

    // ---- block reduction ----
    #pragma unroll
    for (int off = 32; off > 0; off >>= 1) acc += __shfl_down(acc, off);
    const int wave = t >> 6, lane = t & 63;
    if (lane == 0) red[wave] = acc;
    __syncthreads();
    if (t == 0) {
        atomicAdd(out, (red[0] + red[1] + red[2] + red[3]) * (-1.0f / NPIX));
    }
}

extern "C" void kernel_launch(void* const* d_in, const int* in_sizes, int n_in,
                              void* d_out, int out_size, void* d_ws, size_t ws_size,
                              hipStream_t stream) {
    const float* in = (const float*)d_in[0];
    const float* tg = (const float*)d_in[1];
    float* out = (float*)d_out;

    hipMemsetAsync(out, 0, sizeof(float), stream);
    dim3 grid(N_IMG * BANDS);                 // 1024 blocks
    cc_loss_kernel<<<grid, 256, 0, stream>>>(in, tg, out);
}

// Round 5
// 111.511 us; speedup vs baseline: 2.7767x; 2.7767x over previous
//
#include <hip/hip_runtime.h>

#define IMG_H 512
#define IMG_W 512
#define N_IMG 32
#define ROWS  8                    // output rows per wave-band
#define BANDS (IMG_H / ROWS)       // 64 bands per image
#define ITERS (ROWS + 8)           // 16 row-slides per band
#define WROW  520                  // per-array LDS strip: 4 zero-pad + 512 + 4 zero-pad
#define NPIX  (32.0f * 512.0f * 512.0f)

// Load 8 consecutive cols of I and normalized T from row r (zeros if r out of range).
__device__ __forceinline__ void load8(const float* __restrict__ ip,
                                      const float* __restrict__ tp,
                                      int r, int c0, float* I, float* T) {
    if (r >= 0 && r < IMG_H) {
        const float* irow = ip + (ptrdiff_t)r * IMG_W + c0;
        const float* trow = tp + (ptrdiff_t)r * IMG_W + c0;
        float4 a = *(const float4*)(irow);
        float4 b = *(const float4*)(irow + 4);
        float4 c = *(const float4*)(trow);
        float4 d = *(const float4*)(trow + 4);
        I[0]=a.x; I[1]=a.y; I[2]=a.z; I[3]=a.w;
        I[4]=b.x; I[5]=b.y; I[6]=b.z; I[7]=b.w;
        T[0]=fmaf(c.x,0.5f,0.5f); T[1]=fmaf(c.y,0.5f,0.5f);
        T[2]=fmaf(c.z,0.5f,0.5f); T[3]=fmaf(c.w,0.5f,0.5f);
        T[4]=fmaf(d.x,0.5f,0.5f); T[5]=fmaf(d.y,0.5f,0.5f);
        T[6]=fmaf(d.z,0.5f,0.5f); T[7]=fmaf(d.w,0.5f,0.5f);
    } else {
        #pragma unroll
        for (int j = 0; j < 8; ++j) { I[j] = 0.0f; T[j] = 0.0f; }
    }
}

// 9-tap horizontal sliding sums: L = cols c0-4..c0-1, o = own 8, R = cols c0+8..c0+11.
__device__ __forceinline__ void hsum8(const float4 L, const float* o, const float4 R,
                                      float* h) {
    float s = ((L.x + L.y) + (L.z + L.w)) + ((o[0] + o[1]) + (o[2] + o[3])) + o[4];
    h[0] = s;
    s += o[5] - L.x;  h[1] = s;
    s += o[6] - L.y;  h[2] = s;
    s += o[7] - L.z;  h[3] = s;
    s += R.x  - L.w;  h[4] = s;
    s += R.y  - o[0]; h[5] = s;
    s += R.z  - o[1]; h[6] = s;
    s += R.w  - o[2]; h[7] = s;
}

__device__ __forceinline__ float cc_of(float sI, float sT, float sII, float sTT, float sIT) {
    const float inv81 = 1.0f / 81.0f;
    float u     = sI * inv81;
    float w     = sT * inv81;
    float cross = fmaf(-u, sT, sIT);
    float iv    = fmaf(-u, sI, sII);
    float tv    = fmaf(-w, sT, sTT);
    float den   = fmaf(tv, iv, 1e-5f);
    return cross * cross * __builtin_amdgcn_rcpf(den);
}

__global__ __launch_bounds__(256)
void cc_loss_kernel(const float* __restrict__ in, const float* __restrict__ tg,
                    float* __restrict__ out) {
    __shared__ __align__(16) float lds[4][5][WROW];   // wave-private strips, 41.6 KB
    __shared__ float red[4];

    const int t    = threadIdx.x;
    const int w    = t >> 6;
    const int lane = t & 63;

    const int gband = blockIdx.x * 4 + w;      // 0..2047
    const int b     = gband >> 6;              // image (64 bands each)
    const int band  = gband & 63;
    const int r0    = band * ROWS;
    const size_t base = (size_t)b * (IMG_H * IMG_W);
    const float* ip = in + base;
    const float* tp = tg + base;
    const int c0    = lane * 8;                // own image cols c0..c0+7

    float* ldsw = &lds[w][0][0];

    // zero the 8 halo pads per array (once)
    if (lane < 8) {
        const int pos = (lane & 3) + ((lane & 4) ? 516 : 0);
        #pragma unroll
        for (int a = 0; a < 5; ++a) ldsw[a * WROW + pos] = 0.0f;
    }
    __builtin_amdgcn_wave_barrier();

    float vI[8] = {}, vT[8] = {}, vII[8] = {}, vTT[8] = {}, vIT[8] = {};
    float acc = 0.0f;

    float pLI[8], pLT[8], pQI[8], pQT[8];      // current iter: leading + trailing rows
    float nLI[8], nLT[8], nQI[8], nQT[8];      // prefetched next iter

    load8(ip, tp, r0 - 4, c0, pLI, pLT);       // leading row for it=0
    #pragma unroll
    for (int j = 0; j < 8; ++j) { pQI[j] = 0.0f; pQT[j] = 0.0f; }

    for (int it = 0; it < ITERS; ++it) {
        // ---- prefetch next iteration's rows (consumed after ~full iteration) ----
        if (it + 1 < ITERS) {
            load8(ip, tp, r0 - 3 + it, c0, nLI, nLT);                    // next leading
            const int tr = r0 + it - 12;                                 // next trailing
            load8(ip, tp, (it >= 8) ? tr : -1, c0, nQI, nQT);            // active from it+1>=9
        }

        // ---- vertical slide: 8 own cols, 5 arrays ----
        #pragma unroll
        for (int j = 0; j < 8; ++j) {
            float dI = pLI[j] - pQI[j], aI = pLI[j] + pQI[j];
            float dT = pLT[j] - pQT[j], aT = pLT[j] + pQT[j];
            vI[j]  += dI;
            vT[j]  += dT;
            vII[j]  = fmaf(dI, aI, vII[j]);
            vTT[j]  = fmaf(dT, aT, vTT[j]);
            float m = pQI[j] * pQT[j];
            vIT[j]  = fmaf(pLI[j], pLT[j], vIT[j] - m);
        }

        // ---- H phase (wave-local, no s_barrier) ----
        if (it >= 8) {
            float* p0 = ldsw + 0 * WROW + 4 + c0;
            float* p1 = ldsw + 1 * WROW + 4 + c0;
            float* p2 = ldsw + 2 * WROW + 4 + c0;
            float* p3 = ldsw + 3 * WROW + 4 + c0;
            float* p4 = ldsw + 4 * WROW + 4 + c0;
            ((float4*)p0)[0] = make_float4(vI[0],  vI[1],  vI[2],  vI[3]);
            ((float4*)p0)[1] = make_float4(vI[4],  vI[5],  vI[6],  vI[7]);
            ((float4*)p1)[0] = make_float4(vT[0],  vT[1],  vT[2],  vT[3]);
            ((float4*)p1)[1] = make_float4(vT[4],  vT[5],  vT[6],  vT[7]);
            ((float4*)p2)[0] = make_float4(vII[0], vII[1], vII[2], vII[3]);
            ((float4*)p2)[1] = make_float4(vII[4], vII[5], vII[6], vII[7]);
            ((float4*)p3)[0] = make_float4(vTT[0], vTT[1], vTT[2], vTT[3]);
            ((float4*)p3)[1] = make_float4(vTT[4], vTT[5], vTT[6], vTT[7]);
            ((float4*)p4)[0] = make_float4(vIT[0], vIT[1], vIT[2], vIT[3]);
            ((float4*)p4)[1] = make_float4(vIT[4], vIT[5], vIT[6], vIT[7]);
            __builtin_amdgcn_wave_barrier();   // same-wave DS ops are pipe-ordered

            float4 L0 = *(const float4*)(ldsw + 0 * WROW + c0);
            float4 R0 = *(const float4*)(ldsw + 0 * WROW + 12 + c0);
            float4 L1 = *(const float4*)(ldsw + 1 * WROW + c0);
            float4 R1 = *(const float4*)(ldsw + 1 * WROW + 12 + c0);
            float4 L2 = *(const float4*)(ldsw + 2 * WROW + c0);
            float4 R2 = *(const float4*)(ldsw + 2 * WROW + 12 + c0);
            float4 L3 = *(const float4*)(ldsw + 3 * WROW + c0);
            float4 R3 = *(const float4*)(ldsw + 3 * WROW + 12 + c0);
            float4 L4 = *(const float4*)(ldsw + 4 * WROW + c0);
            float4 R4 = *(const float4*)(ldsw + 4 * WROW + 12 + c0);

            float h0[8], h1[8], h2[8], h3[8], h4[8];
            hsum8(L0, vI,  R0, h0);
            hsum8(L1, vT,  R1, h1);
            hsum8(L2, vII, R2, h2);
            hsum8(L3, vTT, R3, h3);
            hsum8(L4, vIT, R4, h4);
            #pragma unroll
            for (int j = 0; j < 8; ++j)
                acc += cc_of(h0[j], h1[j], h2[j], h3[j], h4[j]);
            __builtin_amdgcn_wave_barrier();
        }

        // ---- rotate prefetch ----
        #pragma unroll
        for (int j = 0; j < 8; ++j) {
            pLI[j] = nLI[j]; pLT[j] = nLT[j];
            pQI[j] = nQI[j]; pQT[j] = nQT[j];
        }
    }

    // ---- reduction: wave shuffle, one barrier per block, one atomic ----
    #pragma unroll
    for (int off = 32; off > 0; off >>= 1) acc += __shfl_down(acc, off);
    if (lane == 0) red[w] = acc;
    __syncthreads();
    if (t == 0)
        atomicAdd(out, (red[0] + red[1] + red[2] + red[3]) * (-1.0f / NPIX));
}

extern "C" void kernel_launch(void* const* d_in, const int* in_sizes, int n_in,
                              void* d_out, int out_size, void* d_ws, size_t ws_size,
                              hipStream_t stream) {
    const float* in = (const float*)d_in[0];
    const float* tg = (const float*)d_in[1];
    float* out = (float*)d_out;

    hipMemsetAsync(out, 0, sizeof(float), stream);
    dim3 grid(N_IMG * BANDS / 4);              // 512 blocks x 4 wave-bands
    cc_loss_kernel<<<grid, 256, 0, stream>>>(in, tg, out);
}